// Round 1
// baseline (2712.423 us; speedup 1.0000x reference)
//
#include <hip/hip_runtime.h>
#include <hip/hip_bf16.h>

typedef __bf16 bf16;
typedef __bf16 bf16x8 __attribute__((ext_vector_type(8)));
typedef __bf16 bf16x4 __attribute__((ext_vector_type(4)));
typedef float  f32x4  __attribute__((ext_vector_type(4)));

// Problem dims: N=12000, N_IN=500, E1=E2=500, E3=2000, NZ=10
// Padded:      Kx=512, E1p=E2p=512, E3p=2048, NZp=16

// ---------------- cast kernels ----------------
__global__ void k_cast_bf16(const float* __restrict__ in, bf16* __restrict__ out, long n) {
  long stride = (long)gridDim.x * blockDim.x;
  for (long i = (long)blockIdx.x * blockDim.x + threadIdx.x; i * 8 < n; i += stride) {
    const float4* p = (const float4*)(in + i * 8);
    float4 a = p[0], b = p[1];
    bf16x8 v;
    v[0]=(bf16)a.x; v[1]=(bf16)a.y; v[2]=(bf16)a.z; v[3]=(bf16)a.w;
    v[4]=(bf16)b.x; v[5]=(bf16)b.y; v[6]=(bf16)b.z; v[7]=(bf16)b.w;
    *(bf16x8*)(out + i * 8) = v;
  }
}

// out[r][c] (row-major R x Cp), zero-padded cols >= C
__global__ void k_cast_pad(const float* __restrict__ in, bf16* __restrict__ out,
                           int R, int C, int Cp) {
  int idx = blockIdx.x * blockDim.x + threadIdx.x;
  if (idx >= R * Cp) return;
  int r = idx / Cp, c = idx - r * Cp;
  out[idx] = (c < C) ? (bf16)in[(long)r * C + c] : (bf16)0.f;
}

// W [fi][fo] -> out = W^T padded: [fop][fip]
__global__ void k_cast_wt(const float* __restrict__ W, bf16* __restrict__ out,
                          int fi, int fo, int fip, int fop) {
  int idx = blockIdx.x * blockDim.x + threadIdx.x;
  if (idx >= fop * fip) return;
  int n = idx / fip, k = idx - n * fip;
  out[idx] = (n < fo && k < fi) ? (bf16)W[(long)k * fo + n] : (bf16)0.f;
}

// ---------------- GEMM: C = A[M,K] * B  with B given as B^T layout [N][K] ----------------
// MODE 0: store bf16 C row-major [M][N]   (ld = N)
// MODE 1: store bf16 C^T        [N][M]   (ld = M)
// MODE 2: store f32  C row-major [M][NZ] cols < NZ only (h output)
#define BM 128
#define BN 128
#define BK 64
#define LDT 72   // 64 + 8 halves pad: row stride 144B -> 2-way max on frag reads

template<bool RELU, int MODE>
__global__ __launch_bounds__(256, 2)
void k_gemm(const bf16* __restrict__ A, const bf16* __restrict__ B,
            void* __restrict__ Cout, int M, int N, int K, int NZ)
{
  __shared__ bf16 As[BM * LDT];
  __shared__ bf16 Bs[BN * LDT];

  const int t  = threadIdx.x;
  const int n0 = blockIdx.x * BN;
  const int m0 = blockIdx.y * BM;

  const int lane = t & 63;
  const int wid  = t >> 6;
  const int wm = (wid >> 1) * 64;
  const int wn = (wid & 1) * 64;
  const int lr = lane & 15;   // fragment row (A) / col (B)
  const int kg = lane >> 4;   // k-group 0..3 (8 halves each)

  f32x4 acc[4][4];
#pragma unroll
  for (int i = 0; i < 4; ++i)
#pragma unroll
    for (int j = 0; j < 4; ++j)
#pragma unroll
      for (int r = 0; r < 4; ++r) acc[i][j][r] = 0.f;

  // staging map: 4 threads per row, each 16 halves (2 x 16B); rows t/4 and t/4+64
  const int srow = t >> 2;
  const int sk   = (t & 3) << 4;

  const int nkt = (K + BK - 1) / BK;
  for (int kt = 0; kt < nkt; ++kt) {
    const int kb = kt * BK;
    __syncthreads();
#pragma unroll
    for (int rr = 0; rr < 2; ++rr) {
      const int row = srow + rr * 64;
      const bool kok = (kb + sk) < K;   // K always multiple of 32; 16-half chunk all-or-none
      {
        int4 v0 = {0,0,0,0}, v1 = {0,0,0,0};
        const int gm = m0 + row;
        if (gm < M && kok) {
          const int4* p = (const int4*)(A + (size_t)gm * K + kb + sk);
          v0 = p[0]; v1 = p[1];
        }
        int4* q = (int4*)(As + row * LDT + sk);
        q[0] = v0; q[1] = v1;
      }
      {
        int4 v0 = {0,0,0,0}, v1 = {0,0,0,0};
        const int gn = n0 + row;
        if (gn < N && kok) {
          const int4* p = (const int4*)(B + (size_t)gn * K + kb + sk);
          v0 = p[0]; v1 = p[1];
        }
        int4* q = (int4*)(Bs + row * LDT + sk);
        q[0] = v0; q[1] = v1;
      }
    }
    __syncthreads();

    bf16x8 af[2][4], bfr[2][4];
#pragma unroll
    for (int kk = 0; kk < 2; ++kk) {
#pragma unroll
      for (int mi = 0; mi < 4; ++mi)
        af[kk][mi] = *(const bf16x8*)(As + (wm + mi * 16 + lr) * LDT + kk * 32 + kg * 8);
#pragma unroll
      for (int ni = 0; ni < 4; ++ni)
        bfr[kk][ni] = *(const bf16x8*)(Bs + (wn + ni * 16 + lr) * LDT + kk * 32 + kg * 8);
    }
#pragma unroll
    for (int kk = 0; kk < 2; ++kk)
#pragma unroll
      for (int mi = 0; mi < 4; ++mi)
#pragma unroll
        for (int ni = 0; ni < 4; ++ni)
          acc[mi][ni] = __builtin_amdgcn_mfma_f32_16x16x32_bf16(
              af[kk][mi], bfr[kk][ni], acc[mi][ni], 0, 0, 0);
  }

  // epilogue: D layout col = lane&15, row = (lane>>4)*4 + reg
#pragma unroll
  for (int mi = 0; mi < 4; ++mi) {
#pragma unroll
    for (int ni = 0; ni < 4; ++ni) {
      f32x4 v = acc[mi][ni];
      if (RELU) {
#pragma unroll
        for (int r = 0; r < 4; ++r) v[r] = fmaxf(v[r], 0.f);
      }
      const int row0 = m0 + wm + mi * 16 + kg * 4;
      const int col  = n0 + wn + ni * 16 + lr;
      if constexpr (MODE == 0) {
        if (row0 < M) {   // M%4==0 -> all 4 rows valid together
          bf16* C = (bf16*)Cout;
#pragma unroll
          for (int r = 0; r < 4; ++r) C[(size_t)(row0 + r) * N + col] = (bf16)v[r];
        }
      } else if constexpr (MODE == 1) {
        if (col < N && row0 < M) {
          bf16x4 pk;
#pragma unroll
          for (int r = 0; r < 4; ++r) pk[r] = (bf16)v[r];
          *(bf16x4*)((bf16*)Cout + (size_t)col * M + row0) = pk;
        }
      } else {
        if (col < NZ && row0 < M) {
          float* C = (float*)Cout;
#pragma unroll
          for (int r = 0; r < 4; ++r) C[(size_t)(row0 + r) * NZ + col] = v[r];
        }
      }
    }
  }
}

// ---------------- decode: out[i][j] = sigmoid(dot(h[i], h[j])), h: [Nn][10] f32 ----------------
__global__ void k_decode(const float* __restrict__ h, float* __restrict__ out, int Nn)
{
  const int tx = threadIdx.x & 15, ty = threadIdx.x >> 4;
  const int j0 = blockIdx.x * 64 + tx * 4;
  const int i0 = blockIdx.y * 64 + ty * 4;
  if (j0 >= Nn || i0 >= Nn) return;   // Nn%4==0 -> groups of 4 all-or-none
  float hi[4][10], hj[4][10];
#pragma unroll
  for (int a = 0; a < 4; ++a)
#pragma unroll
    for (int z = 0; z < 10; ++z) {
      hi[a][z] = h[(i0 + a) * 10 + z];
      hj[a][z] = h[(j0 + a) * 10 + z];
    }
#pragma unroll
  for (int a = 0; a < 4; ++a) {
    float4 r;
    float* rp = (float*)&r;
#pragma unroll
    for (int b = 0; b < 4; ++b) {
      float s = 0.f;
#pragma unroll
      for (int z = 0; z < 10; ++z) s += hi[a][z] * hj[b][z];
      rp[b] = 1.f / (1.f + __expf(-s));
    }
    *(float4*)(out + (size_t)(i0 + a) * Nn + j0) = r;
  }
}

// ---------------- launch ----------------
extern "C" void kernel_launch(void* const* d_in, const int* in_sizes, int n_in,
                              void* d_out, int out_size, void* d_ws, size_t ws_size,
                              hipStream_t stream)
{
  const float* x   = (const float*)d_in[0];
  const float* adj = (const float*)d_in[1];
  const float* W1  = (const float*)d_in[2];
  const float* W2  = (const float*)d_in[3];
  const float* W3  = (const float*)d_in[4];
  const float* W4  = (const float*)d_in[5];

  // All scratch inside d_out's A_pred region (576 MB); fully overwritten by decode at the end.
  char* base = (char*)d_out;
  bf16* Ab   = (bf16*)(base);                 // 12000*12000*2 = 288,000,000
  bf16* Buf0 = (bf16*)(base + 288000000);     // up to [2048][12000] = 49,152,000 B
  bf16* Buf1 = (bf16*)(base + 337152000);     // up to [12000][2048] = 49,152,000 B
  bf16* Xb   = (bf16*)(base + 386304000);     // [12000][512] = 12,288,000 B
  bf16* W1t  = (bf16*)(base + 398304000);     // [512][512]
  bf16* W2t  = W1t + 512 * 512;
  bf16* W3t  = W2t + 512 * 512;               // [2048][512]
  bf16* W4t  = W3t + 2048 * 512;              // [16][2048]  (end ~401.5 MB < 576 MB)
  float* hout = (float*)d_out + (size_t)12000 * 12000;
  float* Aout = (float*)d_out;

  // casts
  k_cast_bf16<<<4096, 256, 0, stream>>>(adj, Ab, 144000000L);
  k_cast_pad<<<(12000 * 512 + 255) / 256, 256, 0, stream>>>(x, Xb, 12000, 500, 512);
  k_cast_wt<<<1024, 256, 0, stream>>>(W1, W1t, 500, 500, 512, 512);
  k_cast_wt<<<1024, 256, 0, stream>>>(W2, W2t, 500, 500, 512, 512);
  k_cast_wt<<<4096, 256, 0, stream>>>(W3, W3t, 500, 2000, 512, 2048);
  k_cast_wt<<<128, 256, 0, stream>>>(W4, W4t, 2000, 10, 2048, 16);

  // layer 1
  k_gemm<false,1><<<dim3(4, 94), 256, 0, stream>>>(Xb,  W1t,  Buf0, 12000,  512,   512, 0); // T1^T
  k_gemm<true, 0><<<dim3(4, 94), 256, 0, stream>>>(Ab,  Buf0, Buf1, 12000,  512, 12000, 0); // H1
  // layer 2
  k_gemm<false,1><<<dim3(4, 94), 256, 0, stream>>>(Buf1, W2t, Buf0, 12000,  512,   512, 0); // T2^T
  k_gemm<true, 0><<<dim3(4, 94), 256, 0, stream>>>(Ab,  Buf0, Buf1, 12000,  512, 12000, 0); // H2
  // layer 3
  k_gemm<false,1><<<dim3(16, 94), 256, 0, stream>>>(Buf1, W3t, Buf0, 12000, 2048,   512, 0); // T3^T
  k_gemm<true, 0><<<dim3(16, 94), 256, 0, stream>>>(Ab,  Buf0, Buf1, 12000, 2048, 12000, 0); // H3
  // layer 4
  k_gemm<false,1><<<dim3(1, 94), 256, 0, stream>>>(Buf1, W4t, Buf0, 12000,   16,  2048, 0);  // T4^T
  k_gemm<true, 2><<<dim3(1, 94), 256, 0, stream>>>(Ab,  Buf0, hout, 12000,   16, 12000, 10); // h (f32)

  // decode
  k_decode<<<dim3(188, 188), 256, 0, stream>>>(hout, Aout, 12000);
}

// Round 2
// 2188.446 us; speedup vs baseline: 1.2394x; 1.2394x over previous
//
#include <hip/hip_runtime.h>
#include <hip/hip_bf16.h>
#include <cstdint>

typedef __bf16 bf16;
typedef __bf16 bf16x8 __attribute__((ext_vector_type(8)));
typedef __bf16 bf16x4 __attribute__((ext_vector_type(4)));
typedef float  f32x4  __attribute__((ext_vector_type(4)));

#define KP 12032   // padded neighbor dim (cols of adj, ld of T^T buffers)

__device__ __forceinline__ void llds16(const bf16* g, bf16* s) {
  __builtin_amdgcn_global_load_lds((__attribute__((address_space(1))) void*)g,
                                   (__attribute__((address_space(3))) void*)s,
                                   16, 0, 0);
}

// ---------------- cast kernels ----------------
// adj [12000][12000] f32 -> Ab [12000][KP] bf16, pad cols zeroed
__global__ void k_cast_adj(const float* __restrict__ in, bf16* __restrict__ out) {
  const int r = blockIdx.x;
  const int t = threadIdx.x;
#pragma unroll
  for (int i = 0; i < 6; ++i) {
    const int c = t + 256 * i;          // 8-elem chunk index, 1504 per row
    if (c >= 1504) break;
    bf16x8 v;
    if (c < 1500) {
      const float4* p = (const float4*)(in + (size_t)r * 12000 + c * 8);
      float4 a = p[0], b = p[1];
      v[0]=(bf16)a.x; v[1]=(bf16)a.y; v[2]=(bf16)a.z; v[3]=(bf16)a.w;
      v[4]=(bf16)b.x; v[5]=(bf16)b.y; v[6]=(bf16)b.z; v[7]=(bf16)b.w;
    } else {
#pragma unroll
      for (int j = 0; j < 8; ++j) v[j] = (bf16)0.f;
    }
    *(bf16x8*)(out + (size_t)r * KP + c * 8) = v;
  }
}

__global__ void k_cast_pad(const float* __restrict__ in, bf16* __restrict__ out,
                           int R, int C, int Cp) {
  int idx = blockIdx.x * blockDim.x + threadIdx.x;
  if (idx >= R * Cp) return;
  int r = idx / Cp, c = idx - r * Cp;
  out[idx] = (c < C) ? (bf16)in[(long)r * C + c] : (bf16)0.f;
}

// W [fi][fo] -> out = W^T padded: [fop][fip]
__global__ void k_cast_wt(const float* __restrict__ W, bf16* __restrict__ out,
                          int fi, int fo, int fip, int fop) {
  int idx = blockIdx.x * blockDim.x + threadIdx.x;
  if (idx >= fop * fip) return;
  int n = idx / fip, k = idx - n * fip;
  out[idx] = (n < fo && k < fi) ? (bf16)W[(long)k * fo + n] : (bf16)0.f;
}

// ---------------- GEMM: C = A[M,K] * B, B given transposed [N][K]; ld(A)=ld(B)=K ----------------
// MODE 0: bf16 C row-major [M][ldc], guard row<M && col<N
// MODE 1: bf16 C^T [N][ldc] (ldc = padded M), guard col<N (pad rows get finite garbage)
// K must be a multiple of 64 (buffers pre-padded). Wave grid fixed 2x2.
template<bool RELU, int MODE, int BM, int BN>
__global__ __launch_bounds__(256, 2)
void k_gemm(const bf16* __restrict__ A, const bf16* __restrict__ B,
            bf16* __restrict__ C, int M, int N, int K, int ldc)
{
  constexpr int MI = BM / 32, NI = BN / 32;
  constexpr int CA = BM / 32, CB = BN / 32;   // 1KB chunks per wave
  __shared__ bf16 As[BM * 64];
  __shared__ bf16 Bs[BN * 64];

  // bijective XCD swizzle (m204)
  const int nwg = gridDim.x * gridDim.y;
  int bid = blockIdx.y * gridDim.x + blockIdx.x;
  { const int q = nwg >> 3, r = nwg & 7, x = bid & 7, o = bid >> 3;
    bid = (x < r ? x * (q + 1) : r * (q + 1) + (x - r) * q) + o; }
  const int n0 = (bid % gridDim.x) * BN;
  const int m0 = (bid / gridDim.x) * BM;

  const int t = threadIdx.x, lane = t & 63, wid = t >> 6;
  const int wm = (wid >> 1) * (BM / 2), wn = (wid & 1) * (BN / 2);
  const int lr = lane & 15, kg = lane >> 4;
  const int lA = lane >> 3;                // sub-row within 8-row chunk
  const int cAh = (lane & 7) << 3;         // col offset in halves

  const bf16* ga[CA]; const bf16* gb[CB];
  bf16 *la[CA], *lb[CB];
#pragma unroll
  for (int i = 0; i < CA; ++i) {
    int gm = m0 + (wid * CA + i) * 8 + lA; if (gm > M - 1) gm = M - 1;
    ga[i] = A + (size_t)gm * K + cAh;
    la[i] = As + (wid * CA + i) * 512;     // wave-uniform base
  }
#pragma unroll
  for (int i = 0; i < CB; ++i) {
    int gn = n0 + (wid * CB + i) * 8 + lA; if (gn > N - 1) gn = N - 1;
    gb[i] = B + (size_t)gn * K + cAh;
    lb[i] = Bs + (wid * CB + i) * 512;
  }

  f32x4 acc[MI][NI];
#pragma unroll
  for (int mi = 0; mi < MI; ++mi)
#pragma unroll
    for (int ni = 0; ni < NI; ++ni)
#pragma unroll
      for (int r = 0; r < 4; ++r) acc[mi][ni][r] = 0.f;

  for (int kb = 0; kb < K; kb += 64) {
    __syncthreads();                       // prev iter ds_reads done before overwrite
#pragma unroll
    for (int i = 0; i < CA; ++i) llds16(ga[i] + kb, la[i]);
#pragma unroll
    for (int i = 0; i < CB; ++i) llds16(gb[i] + kb, lb[i]);
    __syncthreads();                       // compiler drains vmcnt before barrier

    bf16x8 af[2][MI], bfr[2][NI];
#pragma unroll
    for (int kk = 0; kk < 2; ++kk) {
#pragma unroll
      for (int mi = 0; mi < MI; ++mi)
        af[kk][mi] = *(const bf16x8*)(As + (wm + mi * 16 + lr) * 64 + kk * 32 + kg * 8);
#pragma unroll
      for (int ni = 0; ni < NI; ++ni)
        bfr[kk][ni] = *(const bf16x8*)(Bs + (wn + ni * 16 + lr) * 64 + kk * 32 + kg * 8);
    }
#pragma unroll
    for (int kk = 0; kk < 2; ++kk)
#pragma unroll
      for (int mi = 0; mi < MI; ++mi)
#pragma unroll
        for (int ni = 0; ni < NI; ++ni)
          acc[mi][ni] = __builtin_amdgcn_mfma_f32_16x16x32_bf16(
              af[kk][mi], bfr[kk][ni], acc[mi][ni], 0, 0, 0);
  }

  // epilogue: D col = lane&15, row = (lane>>4)*4 + reg
#pragma unroll
  for (int mi = 0; mi < MI; ++mi) {
#pragma unroll
    for (int ni = 0; ni < NI; ++ni) {
      f32x4 v = acc[mi][ni];
      if (RELU) {
#pragma unroll
        for (int r = 0; r < 4; ++r) v[r] = fmaxf(v[r], 0.f);
      }
      const int row0 = m0 + wm + mi * 16 + kg * 4;
      const int col  = n0 + wn + ni * 16 + lr;
      if constexpr (MODE == 0) {
        if (row0 < M && col < N) {
#pragma unroll
          for (int r = 0; r < 4; ++r) C[(size_t)(row0 + r) * ldc + col] = (bf16)v[r];
        }
      } else {
        if (col < N) {
          bf16x4 pk;
#pragma unroll
          for (int r = 0; r < 4; ++r) pk[r] = (bf16)v[r];
          *(bf16x4*)(C + (size_t)col * ldc + row0) = pk;
        }
      }
    }
  }
}

// ---------------- h = relu(adj @ T4): Ab [12000][KP] bf16, T4 [12000][16] bf16 -> h [12000][10] f32 ----------------
__global__ void k_h(const bf16* __restrict__ Ab, const bf16* __restrict__ T4,
                    float* __restrict__ hout)
{
  const int lane = threadIdx.x & 63, wid = threadIdx.x >> 6;
  const int r0 = blockIdx.x * 16 + wid * 4;      // 4 rows per wave, 16 per block
  float acc[4][10];
#pragma unroll
  for (int j = 0; j < 4; ++j)
#pragma unroll
    for (int z = 0; z < 10; ++z) acc[j][z] = 0.f;

  for (int i = 0; i < 24; ++i) {
    const int c = i * 64 + lane;                 // 8-wide k-chunk, 1500 total
    if (c < 1500) {
      bf16x8 a0 = *(const bf16x8*)(Ab + (size_t)(r0 + 0) * KP + c * 8);
      bf16x8 a1 = *(const bf16x8*)(Ab + (size_t)(r0 + 1) * KP + c * 8);
      bf16x8 a2 = *(const bf16x8*)(Ab + (size_t)(r0 + 2) * KP + c * 8);
      bf16x8 a3 = *(const bf16x8*)(Ab + (size_t)(r0 + 3) * KP + c * 8);
#pragma unroll
      for (int kk = 0; kk < 8; ++kk) {
        const bf16* tp = T4 + (size_t)(c * 8 + kk) * 16;
        bf16x8 t0 = *(const bf16x8*)(tp);
        bf16x4 t1 = *(const bf16x4*)(tp + 8);
        float tf[10];
#pragma unroll
        for (int z = 0; z < 8; ++z) tf[z] = (float)t0[z];
        tf[8] = (float)t1[0]; tf[9] = (float)t1[1];
        float a[4] = {(float)a0[kk], (float)a1[kk], (float)a2[kk], (float)a3[kk]};
#pragma unroll
        for (int j = 0; j < 4; ++j)
#pragma unroll
          for (int z = 0; z < 10; ++z) acc[j][z] += a[j] * tf[z];
      }
    }
  }
#pragma unroll
  for (int j = 0; j < 4; ++j)
#pragma unroll
    for (int z = 0; z < 10; ++z) {
      float v = acc[j][z];
      for (int m = 1; m < 64; m <<= 1) v += __shfl_xor(v, m, 64);
      acc[j][z] = v;
    }
  if (lane == 0) {
#pragma unroll
    for (int j = 0; j < 4; ++j)
#pragma unroll
      for (int z = 0; z < 10; ++z)
        hout[(size_t)(r0 + j) * 10 + z] = fmaxf(acc[j][z], 0.f);
  }
}

// ---------------- decode: out[i][j] = sigmoid(dot(h[i], h[j])) ----------------
__global__ void k_decode(const float* __restrict__ h, float* __restrict__ out, int Nn)
{
  const int tx = threadIdx.x & 15, ty = threadIdx.x >> 4;
  const int j0 = blockIdx.x * 64 + tx * 4;
  const int i0 = blockIdx.y * 64 + ty * 4;
  if (j0 >= Nn || i0 >= Nn) return;
  float hi[4][10], hj[4][10];
#pragma unroll
  for (int a = 0; a < 4; ++a)
#pragma unroll
    for (int z = 0; z < 10; ++z) {
      hi[a][z] = h[(i0 + a) * 10 + z];
      hj[a][z] = h[(j0 + a) * 10 + z];
    }
#pragma unroll
  for (int a = 0; a < 4; ++a) {
    float4 r;
    float* rp = (float*)&r;
#pragma unroll
    for (int b = 0; b < 4; ++b) {
      float s = 0.f;
#pragma unroll
      for (int z = 0; z < 10; ++z) s += hi[a][z] * hj[b][z];
      rp[b] = 1.f / (1.f + __expf(-s));
    }
    *(float4*)(out + (size_t)(i0 + a) * Nn + j0) = r;
  }
}

// ---------------- launch ----------------
extern "C" void kernel_launch(void* const* d_in, const int* in_sizes, int n_in,
                              void* d_out, int out_size, void* d_ws, size_t ws_size,
                              hipStream_t stream)
{
  const float* x   = (const float*)d_in[0];
  const float* adj = (const float*)d_in[1];
  const float* W1  = (const float*)d_in[2];
  const float* W2  = (const float*)d_in[3];
  const float* W3  = (const float*)d_in[4];
  const float* W4  = (const float*)d_in[5];

  // scratch inside d_out's A_pred region (fully overwritten by decode at the end)
  char* base = (char*)d_out;
  bf16* Ab   = (bf16*)(base);                    // [12000][KP]      288,768,000 B
  bf16* Buf0 = (bf16*)(base + 288768000);        // T^T [<=2048][KP]  49,283,072 B
  bf16* Buf1 = (bf16*)(base + 338051072);        // H   [12000][<=2048] 49,152,000 B
  bf16* Xb   = (bf16*)(base + 387203072);        // [12000][512]     12,288,000 B
  bf16* W1t  = (bf16*)(base + 399491072);        // [512][512]
  bf16* W2t  = W1t + 512 * 512;
  bf16* W3t  = W2t + 512 * 512;                  // [2048][512]
  bf16* W4t  = W3t + 2048 * 512;                 // [16][2048]
  bf16* T4b  = W4t + 16 * 2048;                  // [12000][16]  (end ~403 MB < 576 MB)
  float* hout = (float*)d_out + 144000000L;
  float* Aout = (float*)d_out;

  // casts
  k_cast_adj<<<12000, 256, 0, stream>>>(adj, Ab);
  k_cast_pad<<<(12000 * 512 + 255) / 256, 256, 0, stream>>>(x, Xb, 12000, 500, 512);
  k_cast_wt<<<1024, 256, 0, stream>>>(W1, W1t, 500, 500, 512, 512);
  k_cast_wt<<<1024, 256, 0, stream>>>(W2, W2t, 500, 500, 512, 512);
  k_cast_wt<<<4096, 256, 0, stream>>>(W3, W3t, 500, 2000, 512, 2048);
  k_cast_wt<<<128, 256, 0, stream>>>(W4, W4t, 2000, 10, 2048, 16);

  // layer 1
  k_gemm<false,1,64,128><<<dim3(4, 188), 256, 0, stream>>>(Xb,  W1t, Buf0, 12000, 512, 512, KP);
  k_gemm<true, 0,128,64><<<dim3(8,  94), 256, 0, stream>>>(Ab, Buf0, Buf1, 12000, 512, KP, 512);
  // layer 2
  k_gemm<false,1,64,128><<<dim3(4, 188), 256, 0, stream>>>(Buf1, W2t, Buf0, 12000, 512, 512, KP);
  k_gemm<true, 0,128,64><<<dim3(8,  94), 256, 0, stream>>>(Ab, Buf0, Buf1, 12000, 512, KP, 512);
  // layer 3
  k_gemm<false,1,64,128><<<dim3(16,188), 256, 0, stream>>>(Buf1, W3t, Buf0, 12000, 2048, 512, KP);
  k_gemm<true, 0,128,128><<<dim3(16, 94), 256, 0, stream>>>(Ab, Buf0, Buf1, 12000, 2048, KP, 2048);
  // layer 4: T4 = H3 @ W4 (row-major [12000][16]), then h = relu(adj @ T4)
  k_gemm<false,0,64,128><<<dim3(1, 188), 256, 0, stream>>>(Buf1, W4t, T4b, 12000, 16, 2048, 16);
  k_h<<<750, 256, 0, stream>>>(Ab, T4b, hout);

  // decode
  k_decode<<<dim3(188, 188), 256, 0, stream>>>(hout, Aout, 12000);
}